// Round 7
// baseline (4312.762 us; speedup 1.0000x reference)
//
#include <hip/hip_runtime.h>
#include <cstdint>
#include <cstddef>

// Problem constants
#define B_  4096
#define H_  300
#define T_  43
#define NC_ 80
#define HP  320      // padded hidden/input dim (300 -> 320)
#define KT  640      // fused GEMM K: [x | h]
#define ND  1280     // padded 4H per direction
#define NDD 2560     // both directions
#define TR  304      // hs per-t row length in f16 (300 + 4 zero pad)
#define SB2 (T_ * TR) // hs per-(d,b) stride in f16 = 13072

typedef _Float16 f16;
typedef _Float16 half8 __attribute__((ext_vector_type(8)));
typedef _Float16 half4 __attribute__((ext_vector_type(4)));
typedef float    f32x4 __attribute__((ext_vector_type(4)));
typedef unsigned long long u64;

__device__ __forceinline__ void gl_lds16(const void* g, void* l) {
  __builtin_amdgcn_global_load_lds(
      (const __attribute__((address_space(1))) void*)g,
      (__attribute__((address_space(3))) void*)l, 16, 0, 0);
}
__device__ __forceinline__ float sigmoid_(float x) {
  return 1.f / (1.f + __expf(-x));
}
__device__ __forceinline__ float tanh_fast(float x) {
  x = fminf(fmaxf(x, -15.f), 15.f);
  float e = __expf(2.f * x);
  return (e - 1.f) / (e + 1.f);
}
// Agent-scope atomics: sc1 path -> served at the die-level LLC, coherent
// across the 8 non-coherent per-XCD L2s. Used ONLY for recurrent h + barrier.
__device__ __forceinline__ u64 ld_agent_u64(const u64* p) {
  return __hip_atomic_load(p, __ATOMIC_RELAXED, __HIP_MEMORY_SCOPE_AGENT);
}
__device__ __forceinline__ void st_agent_u64(u64* p, u64 v) {
  __hip_atomic_store(p, v, __ATOMIC_RELAXED, __HIP_MEMORY_SCOPE_AGENT);
}

// ---------------------------------------------------------------------------
// Combined weight packing: Wc[row][k], row = d*1280 + 4*jh + g (gate order
// i,f,g,o), k<320: w_ih (k<300 real), k>=320: w_hh. Zero pad elsewhere.
// bias[row] = b_ih + b_hh.
// ---------------------------------------------------------------------------
__global__ void prep_weights(const float* __restrict__ w_ih,
                             const float* __restrict__ w_hh,
                             const float* __restrict__ b_ih,
                             const float* __restrict__ b_hh,
                             f16* __restrict__ Wc, float* __restrict__ bias) {
  int idx = blockIdx.x * 256 + threadIdx.x;
  const int total = NDD * KT;
  if (idx < total) {
    int row = idx / KT, k = idx % KT;
    int d = row / ND, n = row % ND;
    int jh = n >> 2, g = n & 3;
    float v = 0.f;
    if (jh < H_) {
      if (k < HP) {
        if (k < H_) v = w_ih[((size_t)d * 4 * H_ + g * H_ + jh) * H_ + k];
      } else {
        int kk = k - HP;
        if (kk < H_) v = w_hh[((size_t)d * 4 * H_ + g * H_ + jh) * H_ + kk];
      }
    }
    Wc[idx] = (f16)v;
  }
  if (idx < NDD) {
    int d = idx / ND, n = idx % ND;
    int jh = n >> 2, g = n & 3;
    float v = 0.f;
    if (jh < H_)
      v = b_ih[d * 4 * H_ + g * H_ + jh] + b_hh[d * 4 * H_ + g * H_ + jh];
    bias[idx] = v;
  }
}

// ---------------------------------------------------------------------------
// x [B,H,T] fp32 -> xT[t*B+b][k] f16, k padded to 320 with zeros.
// ---------------------------------------------------------------------------
__global__ void prep_xT(const float* __restrict__ x, f16* __restrict__ xT) {
  __shared__ float tile[64][44];
  int b = blockIdx.x, ch = blockIdx.y;
  int h0 = ch * 64;
  for (int idx = threadIdx.x; idx < 64 * T_; idx += 256) {
    int hh = idx / T_, t = idx % T_;
    float v = 0.f;
    if (h0 + hh < H_) v = x[((size_t)b * H_ + h0 + hh) * T_ + t];
    tile[hh][t] = v;
  }
  __syncthreads();
  for (int idx = threadIdx.x; idx < 64 * T_; idx += 256) {
    int t = idx / 64, hh = idx % 64;
    xT[((size_t)t * B_ + b) * HP + h0 + hh] = (f16)tile[hh][t];
  }
}

// ---------------------------------------------------------------------------
// Persistent LSTM, all 43 steps, NORMAL launch (no cooperative API).
// Dependency closure: h[d, bt-tile] is produced and consumed ONLY by the 10
// blocks (d, wt=0..9, bt) -> per-(d,bt) software barrier of 10 arrivals,
// one counter per step (no reuse/sense issues). Recurrent h through a
// compact ping-pong buffer with agent-scope (sc1, LLC-coherent) atomics.
// Weights/x use the normal cached path (read-only). hs plain stores
// (consumed after kernel end; cross-dispatch flush proven in R3/R4).
// grid (20 n-tiles, 32 b-tiles), 256 thr; launch_bounds(256,3) guarantees
// 3 blocks/CU -> all 640 blocks co-resident (capacity 768): no deadlock.
// ---------------------------------------------------------------------------
__global__ __launch_bounds__(256, 3) void lstm_persist(
    const f16* __restrict__ Wc,     // [2560][640]
    const float* __restrict__ bias, // [2560]
    const f16* __restrict__ xT,     // [43][4096][320]
    f16* __restrict__ hpp,          // ping-pong [2][2][4096][320], memset 0
    float* __restrict__ c,          // [2][300][4096]
    f16* __restrict__ hs,           // [2][4096][43][304]
    unsigned int* __restrict__ bar) // [64][64] step counters, memset 0
{
  __shared__ __attribute__((aligned(16))) char smem[16384];
  f16* As = (f16*)smem;            // 128x32, 8 KB
  f16* Bs = (f16*)(smem + 8192);   // 128x32, 8 KB
  f16* tile = (f16*)smem;          // 32x136 = 8704 B, reused in epilogue

  const int tid = threadIdx.x;
  const int wave = tid >> 6, lane = tid & 63;
  const int nt = blockIdx.x;       // 0..19
  const int bt = blockIdx.y;       // 0..31
  const int d = nt / 10, wt = nt % 10;
  const int lrow4 = lane >> 2, col8 = (lane & 3) << 3;
  const int wm = wave & 1, wn = wave >> 1;
  const int lr = lane & 15, lq = lane >> 4;
  const int kq = lq << 3;

  const f16* Wb = Wc + (size_t)nt * 128 * KT;
  const size_t slab = (size_t)2 * B_ * HP;  // ping-pong slab (f16 elems)
  unsigned int* grpbar = bar + (size_t)(d * 32 + bt) * 64;

  for (int t = 0; t < T_; ++t) {
    const f16* xrow = xT + ((size_t)t * B_ + bt * 128) * HP;
    // read slab (t+1)&1 (t=0 -> slab1, memset zero); write slab t&1
    const f16* hread = hpp + (size_t)((t + 1) & 1) * slab + (size_t)d * B_ * HP;
    f16* hwrite = hpp + (size_t)(t & 1) * slab + (size_t)d * B_ * HP;

    f32x4 acc[4][4];
#pragma unroll
    for (int i = 0; i < 4; i++)
#pragma unroll
      for (int j = 0; j < 4; j++) acc[i][j] = (f32x4){0.f, 0.f, 0.f, 0.f};

    // ---- Phase 1: x-part, kt 0..9, LDS-staged A and B ----
    for (int kt = 0; kt < HP / 32; ++kt) {
      __syncthreads();
#pragma unroll
      for (int i2 = 0; i2 < 2; i2++) {
        int r0 = wave * 32 + i2 * 16;
        gl_lds16(Wb + (size_t)(r0 + lrow4) * KT + kt * 32 + col8, &As[r0 * 32]);
        gl_lds16(xrow + (size_t)(r0 + lrow4) * HP + kt * 32 + col8,
                 &Bs[r0 * 32]);
      }
      __syncthreads();
      half8 af[4], bf8[4];
#pragma unroll
      for (int i = 0; i < 4; i++) {
        af[i] = *(const half8*)&As[(wm * 64 + i * 16 + lr) * 32 + kq];
        bf8[i] = *(const half8*)&Bs[(wn * 64 + i * 16 + lr) * 32 + kq];
      }
#pragma unroll
      for (int i = 0; i < 4; i++)
#pragma unroll
        for (int j = 0; j < 4; j++)
          acc[i][j] = __builtin_amdgcn_mfma_f32_16x16x32_f16(af[i], bf8[j],
                                                             acc[i][j], 0, 0, 0);
    }

    // ---- Phase 2: h-part. Weights via LDS; h fragments direct from the
    // LLC-coherent ping-pong buffer (agent-scope u64 loads). ----
    for (int kt = 0; kt < HP / 32; ++kt) {
      __syncthreads();
#pragma unroll
      for (int i2 = 0; i2 < 2; i2++) {
        int r0 = wave * 32 + i2 * 16;
        gl_lds16(Wb + (size_t)(r0 + lrow4) * KT + HP + kt * 32 + col8,
                 &As[r0 * 32]);
      }
      half8 bf8[4];
#pragma unroll
      for (int j = 0; j < 4; j++) {
        const u64* src = (const u64*)(hread +
            (size_t)(bt * 128 + wn * 64 + j * 16 + lr) * HP + kt * 32 + kq);
        union { u64 q[2]; half8 h; } u;
        u.q[0] = ld_agent_u64(src);
        u.q[1] = ld_agent_u64(src + 1);
        bf8[j] = u.h;
      }
      __syncthreads();
      half8 af[4];
#pragma unroll
      for (int i = 0; i < 4; i++)
        af[i] = *(const half8*)&As[(wm * 64 + i * 16 + lr) * 32 + kq];
#pragma unroll
      for (int i = 0; i < 4; i++)
#pragma unroll
        for (int j = 0; j < 4; j++)
          acc[i][j] = __builtin_amdgcn_mfma_f32_16x16x32_f16(af[i], bf8[j],
                                                             acc[i][j], 0, 0, 0);
    }
    __syncthreads();  // all LDS frag reads done -> tile reuse safe

    // Gate epilogue -> stage hn into LDS tile [jh_local][b_local], stride 136.
#pragma unroll
    for (int i = 0; i < 4; i++) {
      const int jl = wm * 16 + i * 4 + lq;  // 0..31
      const int jh = wt * 32 + jl;
      float4 b4 = {0.f, 0.f, 0.f, 0.f};
      if (jh < H_) b4 = *(const float4*)&bias[d * ND + 4 * jh];
#pragma unroll
      for (int j = 0; j < 4; j++) {
        const int bl = wn * 64 + j * 16 + lr;  // 0..127
        const int b = bt * 128 + bl;
        f16 hnv = (f16)0.f;
        if (jh < H_) {
          float zi = acc[i][j][0] + b4.x;
          float zf = acc[i][j][1] + b4.y;
          float zg = acc[i][j][2] + b4.z;
          float zo = acc[i][j][3] + b4.w;
          const size_t cidx = ((size_t)d * H_ + jh) * B_ + b;
          float co = c[cidx];
          float cn = sigmoid_(zf) * co + sigmoid_(zi) * tanh_fast(zg);
          float hn = sigmoid_(zo) * tanh_fast(cn);
          c[cidx] = cn;
          hnv = (f16)hn;
        }
        tile[jl * 136 + bl] = hnv;
      }
    }
    __syncthreads();

    // Write-out: thread -> (b_local = tid>>1, 16-jh half = tid&1).
    {
      const int bl = tid >> 1, jhalf = tid & 1;
      const int b = bt * 128 + bl;
      const int jh0 = wt * 32 + jhalf * 16;
      union { half8 h; u64 q[2]; } v0, v1;
#pragma unroll
      for (int jj = 0; jj < 8; jj++) {
        v0.h[jj] = tile[(jhalf * 16 + jj) * 136 + bl];
        v1.h[jj] = tile[(jhalf * 16 + 8 + jj) * 136 + bl];
      }
      // recurrent h: agent-scope stores -> LLC (cols 300..319 get zeros)
      u64* hd = (u64*)(hwrite + (size_t)b * HP + jh0);
      st_agent_u64(hd + 0, v0.q[0]);
      st_agent_u64(hd + 1, v0.q[1]);
      st_agent_u64(hd + 2, v1.q[0]);
      st_agent_u64(hd + 3, v1.q[1]);
      // hs row t (plain; consumed by attn after kernel end)
      if (jh0 < H_) {
        f16* sdst = hs + ((size_t)d * B_ + b) * SB2 + (size_t)t * TR + jh0;
        *(half8*)sdst = v0.h;
        *(half8*)(sdst + 8) = v1.h;
      }
    }

    // ---- Group barrier: 10 blocks of (d, bt), counter per step. ----
    if (t < T_ - 1) {
      __syncthreads();  // drains each wave's vmcnt -> h stores ACKed at LLC
      if (tid == 0) {
        __hip_atomic_fetch_add(&grpbar[t], 1u, __ATOMIC_RELEASE,
                               __HIP_MEMORY_SCOPE_AGENT);
        while (__hip_atomic_load(&grpbar[t], __ATOMIC_RELAXED,
                                 __HIP_MEMORY_SCOPE_AGENT) < 10u)
          __builtin_amdgcn_s_sleep(8);
      }
      __syncthreads();
    }
  }
}

// ---------------------------------------------------------------------------
// attn1: alpha[b][t] = softmax_t( sum_h tanh(hs0+hs1) * conv_w[h] ).
// ---------------------------------------------------------------------------
__global__ __launch_bounds__(256) void attn1(const f16* __restrict__ hs,
                                             const float* __restrict__ conv_w,
                                             float* __restrict__ alpha_g) {
  __shared__ float cw[TR];
  __shared__ float red[48];
  const int b = blockIdx.x, tid = threadIdx.x;
  const int wave = tid >> 6, lane = tid & 63;
  for (int k = tid; k < TR; k += 256) cw[k] = (k < H_) ? conv_w[k] : 0.f;
  __syncthreads();

  const half4* s0 = (const half4*)(hs + (size_t)b * SB2);
  const half4* s1 = (const half4*)(hs + (size_t)(B_ + b) * SB2);
  for (int t = wave; t < T_; t += 4) {
    const int base = t * (TR / 4);
    float p = 0.f;
    {
      half4 a = s0[base + lane], cc = s1[base + lane];
#pragma unroll
      for (int r = 0; r < 4; r++)
        p += tanh_fast((float)a[r] + (float)cc[r]) * cw[lane * 4 + r];
    }
    if (lane < 12) {
      half4 a = s0[base + 64 + lane], cc = s1[base + 64 + lane];
#pragma unroll
      for (int r = 0; r < 4; r++)
        p += tanh_fast((float)a[r] + (float)cc[r]) * cw[256 + lane * 4 + r];
    }
#pragma unroll
    for (int o = 32; o; o >>= 1) p += __shfl_down(p, o);
    if (lane == 0) red[t] = p;
  }
  __syncthreads();
  if (tid < 64) {
    float a = (tid < T_) ? red[tid] : -1e30f;
    float mx = a;
#pragma unroll
    for (int o = 32; o; o >>= 1) mx = fmaxf(mx, __shfl_xor(mx, o));
    float e = (tid < T_) ? __expf(a - mx) : 0.f;
    float s = e;
#pragma unroll
    for (int o = 32; o; o >>= 1) s += __shfl_xor(s, o);
    if (tid < T_) alpha_g[(size_t)b * 44 + tid] = e / s;
  }
}

// ---------------------------------------------------------------------------
// attn2: r = sum_t hsum*alpha; hstar = tanh(r); FC logits; softmax.
// ---------------------------------------------------------------------------
__global__ __launch_bounds__(256) void attn2(const f16* __restrict__ hs,
                                             const float* __restrict__ alpha_g,
                                             const float* __restrict__ fc_w,
                                             const float* __restrict__ fc_b,
                                             float* __restrict__ out) {
  __shared__ float al[T_];
  __shared__ float hstar[TR];
  __shared__ float lg[NC_];
  const int b = blockIdx.x, tid = threadIdx.x;
  if (tid < T_) al[tid] = alpha_g[(size_t)b * 44 + tid];
  __syncthreads();

  const f16* s0 = hs + (size_t)b * SB2;
  const f16* s1 = hs + (size_t)(B_ + b) * SB2;
  float r0 = 0.f, r1 = 0.f;
  for (int t = 0; t < T_; t++) {
    const float a = al[t];
    r0 += ((float)s0[t * TR + tid] + (float)s1[t * TR + tid]) * a;
    if (tid < 48)
      r1 += ((float)s0[t * TR + 256 + tid] + (float)s1[t * TR + 256 + tid]) * a;
  }
  hstar[tid] = tanh_fast(r0);
  if (tid < 48) hstar[256 + tid] = tanh_fast(r1);
  __syncthreads();

  const int wave = tid >> 6, lane = tid & 63;
  for (int cls = wave; cls < NC_; cls += 4) {
    float p = 0.f;
    for (int k = lane; k < H_; k += 64) p += hstar[k] * fc_w[(size_t)cls * H_ + k];
#pragma unroll
    for (int o = 32; o; o >>= 1) p += __shfl_down(p, o);
    if (lane == 0) lg[cls] = p + fc_b[cls];
  }
  __syncthreads();
  if (tid < 64) {
    float a0 = (tid < 40) ? lg[tid] : -1e30f;
    float a1 = (tid < 40) ? lg[tid + 40] : -1e30f;
    float mx = fmaxf(a0, a1);
#pragma unroll
    for (int o = 32; o; o >>= 1) mx = fmaxf(mx, __shfl_xor(mx, o));
    float e0 = (tid < 40) ? __expf(a0 - mx) : 0.f;
    float e1 = (tid < 40) ? __expf(a1 - mx) : 0.f;
    float s = e0 + e1;
#pragma unroll
    for (int o = 32; o; o >>= 1) s += __shfl_xor(s, o);
    if (tid < 40) {
      out[(size_t)b * NC_ + tid] = e0 / s;
      out[(size_t)b * NC_ + tid + 40] = e1 / s;
    }
  }
}

// ---------------------------------------------------------------------------
extern "C" void kernel_launch(void* const* d_in, const int* in_sizes, int n_in,
                              void* d_out, int out_size, void* d_ws, size_t ws_size,
                              hipStream_t stream) {
  const float* x      = (const float*)d_in[0];
  const float* w_ih   = (const float*)d_in[1];
  const float* w_hh   = (const float*)d_in[2];
  const float* b_ih   = (const float*)d_in[3];
  const float* b_hh   = (const float*)d_in[4];
  const float* conv_w = (const float*)d_in[5];
  const float* fc_w   = (const float*)d_in[6];
  const float* fc_b   = (const float*)d_in[7];
  float* out = (float*)d_out;

  // Workspace carve (~351 MB)
  char* p = (char*)d_ws;
  f16* Wc = (f16*)p;    p += (size_t)NDD * KT * sizeof(f16);           // 3.3 MB
  float* bias = (float*)p; p += (size_t)NDD * sizeof(float);           // 10 KB
  p = (char*)(((uintptr_t)p + 255) & ~(uintptr_t)255);
  f16* xT = (f16*)p;    p += (size_t)T_ * B_ * HP * sizeof(f16);       // 112.7 MB
  float* c = (float*)p; p += (size_t)2 * B_ * H_ * sizeof(float);      // 9.8 MB
  f16* hpp = (f16*)p;   p += (size_t)2 * 2 * B_ * HP * sizeof(f16);    // 10.5 MB
  f16* hs = (f16*)p;    p += ((size_t)2 * B_ * SB2 + 64) * sizeof(f16);// 214.2 MB
  float* alpha_g = (float*)p; p += (size_t)B_ * 44 * sizeof(float);    // 0.72 MB
  p = (char*)(((uintptr_t)p + 255) & ~(uintptr_t)255);
  unsigned int* bar = (unsigned int*)p; p += (size_t)64 * 64 * sizeof(unsigned);

  hipMemsetAsync(hpp, 0, (size_t)2 * 2 * B_ * HP * sizeof(f16), stream);
  hipMemsetAsync(c, 0, (size_t)2 * B_ * H_ * sizeof(float), stream);
  hipMemsetAsync(bar, 0, (size_t)64 * 64 * sizeof(unsigned), stream);

  prep_weights<<<(NDD * KT + 255) / 256, 256, 0, stream>>>(
      w_ih, w_hh, b_ih, b_hh, Wc, bias);
  prep_xT<<<dim3(B_, 5), 256, 0, stream>>>(x, xT);

  // Persistent recurrence: 640 blocks, 3/CU guaranteed by launch_bounds.
  lstm_persist<<<dim3(20, 32), 256, 0, stream>>>(Wc, bias, xT, hpp, c, hs, bar);

  attn1<<<B_, 256, 0, stream>>>(hs, conv_w, alpha_g);
  attn2<<<B_, 256, 0, stream>>>(hs, alpha_g, fc_w, fc_b, out);
}